// Round 2
// baseline (736.604 us; speedup 1.0000x reference)
//
#include <hip/hip_runtime.h>
#include <hip/hip_bf16.h>

#define NN 50000
#define EE 400000

typedef __bf16 bf16_8 __attribute__((ext_vector_type(8)));
typedef float f32x4 __attribute__((ext_vector_type(4)));

// ---------------------------------------------------------------- CSR build
__global__ __launch_bounds__(256) void count_kernel(const int* __restrict__ dst,
                                                    int* __restrict__ cnt) {
  int e = blockIdx.x * 256 + threadIdx.x;
  if (e < EE) atomicAdd(&cnt[dst[e]], 1);
}

__global__ __launch_bounds__(256) void scan1_kernel(const int* __restrict__ cnt,
                                                    int* __restrict__ scanbuf,
                                                    int* __restrict__ blocksum) {
  __shared__ int s[256];
  int t = threadIdx.x;
  int idx = blockIdx.x * 256 + t;
  int c = (idx < NN) ? cnt[idx] : 0;
  s[t] = c;
  __syncthreads();
  for (int d = 1; d < 256; d <<= 1) {
    int v = (t >= d) ? s[t - d] : 0;
    __syncthreads();
    s[t] += v;
    __syncthreads();
  }
  if (idx < NN) scanbuf[idx] = s[t];
  if (t == 255) blocksum[blockIdx.x] = s[255];
}

__global__ __launch_bounds__(256) void scan2_kernel(const int* __restrict__ blocksum,
                                                    int* __restrict__ blockoff, int nb) {
  __shared__ int s[256];
  int t = threadIdx.x;
  int c = (t < nb) ? blocksum[t] : 0;
  s[t] = c;
  __syncthreads();
  for (int d = 1; d < 256; d <<= 1) {
    int v = (t >= d) ? s[t - d] : 0;
    __syncthreads();
    s[t] += v;
    __syncthreads();
  }
  if (t < nb) blockoff[t] = s[t] - c;  // exclusive
}

__global__ __launch_bounds__(256) void scan3_kernel(const int* __restrict__ scanbuf,
                                                    const int* __restrict__ cnt,
                                                    const int* __restrict__ blockoff,
                                                    int* __restrict__ off,
                                                    int* __restrict__ cur) {
  int idx = blockIdx.x * 256 + threadIdx.x;
  if (idx < NN) {
    int o = blockoff[blockIdx.x] + scanbuf[idx] - cnt[idx];
    off[idx] = o;
    cur[idx] = o;
  }
  if (idx == 0) off[NN] = EE;
}

__global__ __launch_bounds__(256) void fill_kernel(const int* __restrict__ dst,
                                                   int* __restrict__ cur,
                                                   int* __restrict__ eids) {
  int e = blockIdx.x * 256 + threadIdx.x;
  if (e < EE) {
    int p = atomicAdd(&cur[dst[e]], 1);
    eids[p] = e;
  }
}

// ---------------------------------------------------------------- dtype prep
// fp32 -> bf16, 8 elements/thread
__global__ __launch_bounds__(256) void f2b_kernel(const float* __restrict__ in,
                                                  __bf16* __restrict__ out, int n8) {
  int i = blockIdx.x * 256 + threadIdx.x;
  if (i >= n8) return;
  const float4* p = (const float4*)in + (size_t)i * 2;
  float4 a = p[0], b = p[1];
  bf16_8 v = {(__bf16)a.x, (__bf16)a.y, (__bf16)a.z, (__bf16)a.w,
              (__bf16)b.x, (__bf16)b.y, (__bf16)b.z, (__bf16)b.w};
  *(bf16_8*)(out + (size_t)i * 8) = v;
}

// Bt0 (512 x 64) bf16: rows 0..255 = W0^T, rows 256..511 = Wres0^T (fp32 src)
__global__ __launch_bounds__(256) void tr0_kernel(const float* __restrict__ W0,
                                                  const float* __restrict__ Wres,
                                                  __bf16* __restrict__ Bt) {
  int idx = blockIdx.x * 256 + threadIdx.x;  // 512*64
  if (idx >= 512 * 64) return;
  int j = idx >> 6, k = idx & 63;
  float v = (j < 256) ? W0[k * 256 + j] : Wres[k * 256 + (j - 256)];
  Bt[idx] = (__bf16)v;
}

// Bt1 (256 x 256) bf16 = W1^T (fp32 src)
__global__ __launch_bounds__(256) void tr1_kernel(const float* __restrict__ W1,
                                                  __bf16* __restrict__ Bt) {
  int idx = blockIdx.x * 256 + threadIdx.x;  // 256*256
  if (idx >= 256 * 256) return;
  int j = idx >> 8, k = idx & 255;
  Bt[idx] = (__bf16)W1[k * 256 + j];
}

// Ve[f][h] = sum_d We[f][h*64+d] * ae[h][d]   (64 x 4 fp32)
__global__ void ve_kernel(const float* __restrict__ We, const float* __restrict__ ae,
                          float* __restrict__ Ve) {
  int t = threadIdx.x;  // 256
  int f = t >> 2, h = t & 3;
  float s = 0.f;
  for (int d = 0; d < 64; ++d)
    s += We[f * 256 + h * 64 + d] * ae[h * 64 + d];
  Ve[f * 4 + h] = s;
}

// ---------------------------------------------------------------- MFMA GEMM
// C[M x NC] = A[M x K] @ B[K x NC], B given transposed (Bt: NC x K, row-major).
// cols < 256 -> ft (bf16); cols >= 256 -> base = val + bias[col-256] (layer 0).
#define LDK 40
__global__ __launch_bounds__(256) void gemm_kernel(const __bf16* __restrict__ A,
                                                   const __bf16* __restrict__ Bt,
                                                   __bf16* __restrict__ ft,
                                                   __bf16* __restrict__ base,
                                                   const float* __restrict__ bias,
                                                   int M, int K) {
  __shared__ __align__(16) __bf16 Al[64 * LDK];
  __shared__ __align__(16) __bf16 Bl[64 * LDK];
  int tid = threadIdx.x;
  int wav = tid >> 6, lane = tid & 63;
  int quad = lane >> 4, l16 = lane & 15;
  int bm = blockIdx.x * 64;
  int bn = blockIdx.y * 64;
  int sr = tid >> 2;          // staging row 0..63
  int sk = (tid & 3) << 3;    // staging k offset 0,8,16,24

  f32x4 acc[4] = {{0, 0, 0, 0}, {0, 0, 0, 0}, {0, 0, 0, 0}, {0, 0, 0, 0}};

  for (int k0 = 0; k0 < K; k0 += 32) {
    uint4 av = {0, 0, 0, 0};
    int arow = bm + sr;
    if (arow < M) av = *(const uint4*)(A + (size_t)arow * K + k0 + sk);
    uint4 bv = *(const uint4*)(Bt + (size_t)(bn + sr) * K + k0 + sk);
    __syncthreads();
    *(uint4*)&Al[sr * LDK + sk] = av;
    *(uint4*)&Bl[sr * LDK + sk] = bv;
    __syncthreads();
    bf16_8 af = *(const bf16_8*)&Al[(wav * 16 + l16) * LDK + quad * 8];
#pragma unroll
    for (int nt = 0; nt < 4; ++nt) {
      bf16_8 bf = *(const bf16_8*)&Bl[(nt * 16 + l16) * LDK + quad * 8];
      acc[nt] = __builtin_amdgcn_mfma_f32_16x16x32_bf16(af, bf, acc[nt], 0, 0, 0);
    }
  }

  int row0 = bm + wav * 16 + quad * 4;
#pragma unroll
  for (int nt = 0; nt < 4; ++nt) {
    int col = bn + nt * 16 + l16;
#pragma unroll
    for (int r = 0; r < 4; ++r) {
      int row = row0 + r;
      if (row < M) {
        float v = acc[nt][r];
        if (col < 256)
          ft[(size_t)row * 256 + col] = (__bf16)v;
        else
          base[(size_t)row * 256 + (col - 256)] = (__bf16)(v + bias[col - 256]);
      }
    }
  }
}

// ---------------------------------------------------------------- el / er
__global__ __launch_bounds__(256) void elr_kernel(const __bf16* __restrict__ ft,
                                                  const float* __restrict__ al,
                                                  const float* __restrict__ ar,
                                                  float* __restrict__ el,
                                                  float* __restrict__ er) {
  int w = threadIdx.x >> 6, lane = threadIdx.x & 63;
  int n = blockIdx.x * 4 + w;
  if (n >= NN) return;
  const __bf16* row = ft + (size_t)n * 256;
#pragma unroll
  for (int h = 0; h < 4; ++h) {
    float f = (float)row[h * 64 + lane];
    float pl = f * al[h * 64 + lane];
    float pr = f * ar[h * 64 + lane];
#pragma unroll
    for (int o = 32; o > 0; o >>= 1) {
      pl += __shfl_xor(pl, o);
      pr += __shfl_xor(pr, o);
    }
    if (lane == 0) {
      el[n * 4 + h] = pl;
      er[n * 4 + h] = pr;
    }
  }
}

// ---------------------------------------------------------------- edge scores
__global__ __launch_bounds__(256) void edge_kernel(const float* __restrict__ ef,
                                                   const int* __restrict__ src,
                                                   const int* __restrict__ dst,
                                                   const float* __restrict__ Ve,
                                                   const float* __restrict__ el,
                                                   const float* __restrict__ er,
                                                   float* __restrict__ escore) {
  __shared__ float Vs[256];
  Vs[threadIdx.x] = Ve[threadIdx.x];
  __syncthreads();
  int e = blockIdx.x * 256 + threadIdx.x;
  if (e >= EE) return;
  float eh0 = 0, eh1 = 0, eh2 = 0, eh3 = 0;
  const float* row = ef + (size_t)e * 64;
#pragma unroll
  for (int i0 = 0; i0 < 64; i0 += 4) {
    float4 v = *(const float4*)(row + i0);
    float xs[4] = {v.x, v.y, v.z, v.w};
#pragma unroll
    for (int j = 0; j < 4; ++j) {
      float x = xs[j];
      const float* vp = &Vs[(i0 + j) * 4];
      eh0 += x * vp[0];
      eh1 += x * vp[1];
      eh2 += x * vp[2];
      eh3 += x * vp[3];
    }
  }
  int s = src[e], d = dst[e];
  float4 l = *(const float4*)(el + (size_t)s * 4);
  float4 r = *(const float4*)(er + (size_t)d * 4);
  float4 o;
  o.x = l.x + r.x + eh0;
  o.y = l.y + r.y + eh1;
  o.z = l.z + r.z + eh2;
  o.w = l.w + r.w + eh3;
  o.x = o.x > 0.f ? o.x : 0.2f * o.x;
  o.y = o.y > 0.f ? o.y : 0.2f * o.y;
  o.z = o.z > 0.f ? o.z : 0.2f * o.z;
  o.w = o.w > 0.f ? o.w : 0.2f * o.w;
  *(float4*)(escore + (size_t)e * 4) = o;
}

// ---------------------------------------------------------------- softmax-agg
// One block per dst node. wave w == head w. LAYER 0: +base, ELU -> outb (bf16,
// may alias prev: per-thread read-then-write of the same slot only).
// LAYER 1: +prev+b1, mean over heads -> outf (N x 64 fp32).
template <int LAYER>
__global__ __launch_bounds__(256) void agg_kernel(const int* __restrict__ off,
                                                  const int* __restrict__ eids,
                                                  const int* __restrict__ src,
                                                  const float* __restrict__ escore,
                                                  const __bf16* __restrict__ ft,
                                                  const __bf16* prev,
                                                  const float* __restrict__ bias,
                                                  __bf16* outb,
                                                  float* __restrict__ outf) {
  __shared__ float red[256];
  int n = blockIdx.x;
  int t = threadIdx.x, h = t >> 6, lane = t & 63;
  int beg = off[n], end = off[n + 1];

  float m = -1e30f;
  for (int i = beg + lane; i < end; i += 64) m = fmaxf(m, escore[eids[i] * 4 + h]);
#pragma unroll
  for (int o = 32; o > 0; o >>= 1) m = fmaxf(m, __shfl_xor(m, o));

  float den = 0.f;
  for (int i = beg + lane; i < end; i += 64) den += __expf(escore[eids[i] * 4 + h] - m);
#pragma unroll
  for (int o = 32; o > 0; o >>= 1) den += __shfl_xor(den, o);
  float inv = (end > beg) ? 1.0f / den : 0.0f;

  float acc = 0.f;
  for (int i = beg; i < end; ++i) {
    int eid = eids[i];
    float a = __expf(escore[eid * 4 + h] - m);
    float v = (float)ft[(size_t)src[eid] * 256 + h * 64 + lane];
    acc += a * v;
  }
  acc *= inv;

  if (LAYER == 0) {
    float v = acc + (float)prev[(size_t)n * 256 + t];
    v = v > 0.f ? v : (__expf(v) - 1.0f);  // ELU
    outb[(size_t)n * 256 + t] = (__bf16)v;
  } else {
    float v = acc + (float)prev[(size_t)n * 256 + t] + bias[t];
    red[t] = v;
    __syncthreads();
    if (t < 64) {
      float o = 0.25f * (red[t] + red[t + 64] + red[t + 128] + red[t + 192]);
      outf[(size_t)n * 64 + t] = o;
    }
  }
}

// ---------------------------------------------------------------- launch
extern "C" void kernel_launch(void* const* d_in, const int* in_sizes, int n_in,
                              void* d_out, int out_size, void* d_ws, size_t ws_size,
                              hipStream_t stream) {
  const float* features  = (const float*)d_in[0];
  const float* edge_feat = (const float*)d_in[1];
  const int*   src       = (const int*)d_in[2];
  const int*   dst       = (const int*)d_in[3];
  const float* W0    = (const float*)d_in[4];
  const float* We0   = (const float*)d_in[5];
  const float* al0   = (const float*)d_in[6];
  const float* ar0   = (const float*)d_in[7];
  const float* ae0   = (const float*)d_in[8];
  const float* b0    = (const float*)d_in[9];
  const float* Wres0 = (const float*)d_in[10];
  const float* W1    = (const float*)d_in[11];
  const float* We1   = (const float*)d_in[12];
  const float* al1   = (const float*)d_in[13];
  const float* ar1   = (const float*)d_in[14];
  const float* ae1   = (const float*)d_in[15];
  const float* b1    = (const float*)d_in[16];
  float* out = (float*)d_out;

  char* ws = (char*)d_ws;
  size_t o = 0;
  auto alloc = [&](size_t bytes) {
    void* p = ws + o;
    o = (o + bytes + 255) & ~(size_t)255;
    return p;
  };
  int*    cnt      = (int*)alloc((size_t)NN * 4);
  int*    scanbuf  = (int*)alloc((size_t)NN * 4);
  int*    blocksum = (int*)alloc(256 * 4);
  int*    blockoff = (int*)alloc(256 * 4);
  int*    off      = (int*)alloc((size_t)(NN + 1) * 4);
  int*    cur      = (int*)alloc((size_t)NN * 4);
  int*    eids     = (int*)alloc((size_t)EE * 4);
  float*  el       = (float*)alloc((size_t)NN * 4 * 4);
  float*  er       = (float*)alloc((size_t)NN * 4 * 4);
  float*  escore   = (float*)alloc((size_t)EE * 4 * 4);
  float*  Ve       = (float*)alloc(256 * 4);
  __bf16* Bt       = (__bf16*)alloc((size_t)65536 * 2);
  __bf16* fbf      = (__bf16*)alloc((size_t)NN * 64 * 2);
  __bf16* ft       = (__bf16*)alloc((size_t)NN * 256 * 2);
  __bf16* base     = (__bf16*)alloc((size_t)NN * 256 * 2);  // h1 aliases base
  __bf16* h1       = base;

  const int EB = (EE + 255) / 256;   // 1563
  const int NB = (NN + 255) / 256;   // 196
  const int MG = (NN + 63) / 64;     // 782

  // CSR by dst (same for both layers)
  hipMemsetAsync(cnt, 0, (size_t)NN * 4, stream);
  count_kernel<<<EB, 256, 0, stream>>>(dst, cnt);
  scan1_kernel<<<NB, 256, 0, stream>>>(cnt, scanbuf, blocksum);
  scan2_kernel<<<1, 256, 0, stream>>>(blocksum, blockoff, NB);
  scan3_kernel<<<NB, 256, 0, stream>>>(scanbuf, cnt, blockoff, off, cur);
  fill_kernel<<<EB, 256, 0, stream>>>(dst, cur, eids);

  // ---- layer 0
  f2b_kernel<<<(NN * 64 / 8 + 255) / 256, 256, 0, stream>>>(features, fbf, NN * 64 / 8);
  tr0_kernel<<<(512 * 64) / 256, 256, 0, stream>>>(W0, Wres0, Bt);
  gemm_kernel<<<dim3(MG, 8), 256, 0, stream>>>(fbf, Bt, ft, base, b0, NN, 64);
  elr_kernel<<<NN / 4, 256, 0, stream>>>(ft, al0, ar0, el, er);
  ve_kernel<<<1, 256, 0, stream>>>(We0, ae0, Ve);
  edge_kernel<<<EB, 256, 0, stream>>>(edge_feat, src, dst, Ve, el, er, escore);
  agg_kernel<0><<<NN, 256, 0, stream>>>(off, eids, src, escore, ft, base, nullptr, h1, nullptr);

  // ---- layer 1
  tr1_kernel<<<(256 * 256) / 256, 256, 0, stream>>>(W1, Bt);
  gemm_kernel<<<dim3(MG, 4), 256, 0, stream>>>(h1, Bt, ft, nullptr, nullptr, NN, 256);
  elr_kernel<<<NN / 4, 256, 0, stream>>>(ft, al1, ar1, el, er);
  ve_kernel<<<1, 256, 0, stream>>>(We1, ae1, Ve);
  edge_kernel<<<EB, 256, 0, stream>>>(edge_feat, src, dst, Ve, el, er, escore);
  agg_kernel<1><<<NN, 256, 0, stream>>>(off, eids, src, escore, ft, h1, b1, nullptr, out);
}

// Round 3
// 502.201 us; speedup vs baseline: 1.4668x; 1.4668x over previous
//
#include <hip/hip_runtime.h>
#include <hip/hip_bf16.h>

#define NN 50000
#define EE 400000
#define CHUNK 192

typedef __bf16 bf16_8 __attribute__((ext_vector_type(8)));
typedef float f32x4 __attribute__((ext_vector_type(4)));

// ---------------------------------------------------------------- CSR build
__global__ __launch_bounds__(256) void count_kernel(const int* __restrict__ dst,
                                                    int* __restrict__ cnt) {
  int e = blockIdx.x * 256 + threadIdx.x;
  if (e < EE) atomicAdd(&cnt[dst[e]], 1);
}

__global__ __launch_bounds__(256) void scan1_kernel(const int* __restrict__ cnt,
                                                    int* __restrict__ scanbuf,
                                                    int* __restrict__ blocksum) {
  __shared__ int s[256];
  int t = threadIdx.x;
  int idx = blockIdx.x * 256 + t;
  int c = (idx < NN) ? cnt[idx] : 0;
  s[t] = c;
  __syncthreads();
  for (int d = 1; d < 256; d <<= 1) {
    int v = (t >= d) ? s[t - d] : 0;
    __syncthreads();
    s[t] += v;
    __syncthreads();
  }
  if (idx < NN) scanbuf[idx] = s[t];
  if (t == 255) blocksum[blockIdx.x] = s[255];
}

__global__ __launch_bounds__(256) void scan2_kernel(const int* __restrict__ blocksum,
                                                    int* __restrict__ blockoff, int nb) {
  __shared__ int s[256];
  int t = threadIdx.x;
  int c = (t < nb) ? blocksum[t] : 0;
  s[t] = c;
  __syncthreads();
  for (int d = 1; d < 256; d <<= 1) {
    int v = (t >= d) ? s[t - d] : 0;
    __syncthreads();
    s[t] += v;
    __syncthreads();
  }
  if (t < nb) blockoff[t] = s[t] - c;  // exclusive
}

__global__ __launch_bounds__(256) void scan3_kernel(const int* __restrict__ scanbuf,
                                                    const int* __restrict__ cnt,
                                                    const int* __restrict__ blockoff,
                                                    int* __restrict__ off,
                                                    int* __restrict__ cur) {
  int idx = blockIdx.x * 256 + threadIdx.x;
  if (idx < NN) {
    int o = blockoff[blockIdx.x] + scanbuf[idx] - cnt[idx];
    off[idx] = o;
    cur[idx] = o;
  }
  if (idx == 0) off[NN] = EE;
}

// also records pos[e] (slot of edge e) and src_csr[p] = src[e]
__global__ __launch_bounds__(256) void fill_kernel(const int* __restrict__ src,
                                                   const int* __restrict__ dst,
                                                   int* __restrict__ cur,
                                                   int* __restrict__ pos,
                                                   int* __restrict__ srcc) {
  int e = blockIdx.x * 256 + threadIdx.x;
  if (e < EE) {
    int p = atomicAdd(&cur[dst[e]], 1);
    pos[e] = p;
    srcc[p] = src[e];
  }
}

// ---------------------------------------------------------------- prep (fused)
// blocks [0,1563): f2b features->fbf; [1563,1691): tr0; [1691,1947): tr1;
// 1947: ve0; 1948: ve1
__global__ __launch_bounds__(256) void prep_kernel(
    const float* __restrict__ features, __bf16* __restrict__ fbf,
    const float* __restrict__ W0, const float* __restrict__ Wres0, __bf16* __restrict__ Bt0,
    const float* __restrict__ W1, __bf16* __restrict__ Bt1,
    const float* __restrict__ We0, const float* __restrict__ ae0, float* __restrict__ Ve0,
    const float* __restrict__ We1, const float* __restrict__ ae1, float* __restrict__ Ve1) {
  int b = blockIdx.x;
  int t = threadIdx.x;
  if (b < 1563) {                       // fp32 -> bf16, 8 elems/thread
    int i = b * 256 + t;
    if (i < NN * 64 / 8) {
      const float4* p = (const float4*)features + (size_t)i * 2;
      float4 a = p[0], c = p[1];
      bf16_8 v = {(__bf16)a.x, (__bf16)a.y, (__bf16)a.z, (__bf16)a.w,
                  (__bf16)c.x, (__bf16)c.y, (__bf16)c.z, (__bf16)c.w};
      *(bf16_8*)(fbf + (size_t)i * 8) = v;
    }
  } else if (b < 1563 + 128) {          // Bt0 (512x64): W0^T | Wres0^T
    int idx = (b - 1563) * 256 + t;
    int j = idx >> 6, k = idx & 63;
    float v = (j < 256) ? W0[k * 256 + j] : Wres0[k * 256 + (j - 256)];
    Bt0[idx] = (__bf16)v;
  } else if (b < 1563 + 128 + 256) {    // Bt1 (256x256) = W1^T
    int idx = (b - 1563 - 128) * 256 + t;
    int j = idx >> 8, k = idx & 255;
    Bt1[idx] = (__bf16)W1[k * 256 + j];
  } else if (b == 1563 + 384) {         // Ve0[f][h] = sum_d We0[f][h*64+d]*ae0[h][d]
    int f = t >> 2, h = t & 3;
    float s = 0.f;
    for (int d = 0; d < 64; ++d) s += We0[f * 256 + h * 64 + d] * ae0[h * 64 + d];
    Ve0[f * 4 + h] = s;
  } else {                              // Ve1
    int f = t >> 2, h = t & 3;
    float s = 0.f;
    for (int d = 0; d < 64; ++d) s += We1[f * 256 + h * 64 + d] * ae1[h * 64 + d];
    Ve1[f * 4 + h] = s;
  }
}

// ---------------------------------------------------------------- MFMA GEMM
// C[M x NC] = A @ B, Bt: NC x K row-major. cols<256 -> ft (bf16) + fused el/er;
// cols>=256 -> base = val + bias[col-256] (layer 0 residual).
#define LDK 40
__global__ __launch_bounds__(256) void gemm_kernel(const __bf16* __restrict__ A,
                                                   const __bf16* __restrict__ Bt,
                                                   __bf16* __restrict__ ft,
                                                   __bf16* __restrict__ base,
                                                   const float* __restrict__ bias,
                                                   const float* __restrict__ al,
                                                   const float* __restrict__ ar,
                                                   float* __restrict__ el,
                                                   float* __restrict__ er,
                                                   int M, int K) {
  __shared__ __align__(16) __bf16 Al[64 * LDK];
  __shared__ __align__(16) __bf16 Bl[64 * LDK];
  int tid = threadIdx.x;
  int wav = tid >> 6, lane = tid & 63;
  int quad = lane >> 4, l16 = lane & 15;
  int bm = blockIdx.x * 64;
  int bn = blockIdx.y * 64;
  int sr = tid >> 2;
  int sk = (tid & 3) << 3;

  f32x4 acc[4] = {{0, 0, 0, 0}, {0, 0, 0, 0}, {0, 0, 0, 0}, {0, 0, 0, 0}};

  for (int k0 = 0; k0 < K; k0 += 32) {
    uint4 av = {0, 0, 0, 0};
    int arow = bm + sr;
    if (arow < M) av = *(const uint4*)(A + (size_t)arow * K + k0 + sk);
    uint4 bv = *(const uint4*)(Bt + (size_t)(bn + sr) * K + k0 + sk);
    __syncthreads();
    *(uint4*)&Al[sr * LDK + sk] = av;
    *(uint4*)&Bl[sr * LDK + sk] = bv;
    __syncthreads();
    bf16_8 af = *(const bf16_8*)&Al[(wav * 16 + l16) * LDK + quad * 8];
#pragma unroll
    for (int nt = 0; nt < 4; ++nt) {
      bf16_8 bf = *(const bf16_8*)&Bl[(nt * 16 + l16) * LDK + quad * 8];
      acc[nt] = __builtin_amdgcn_mfma_f32_16x16x32_bf16(af, bf, acc[nt], 0, 0, 0);
    }
  }

  int row0 = bm + wav * 16 + quad * 4;

  // fused el/er: this block owns head hb for rows row0..row0+3 (per lane group)
  if (bn < 256) {
    int hb = bn >> 6;
#pragma unroll
    for (int r = 0; r < 4; ++r) {
      float pl = 0.f, pr = 0.f;
#pragma unroll
      for (int nt = 0; nt < 4; ++nt) {
        float v = acc[nt][r];
        int d = nt * 16 + l16;
        pl += v * al[hb * 64 + d];
        pr += v * ar[hb * 64 + d];
      }
#pragma unroll
      for (int o2 = 8; o2 > 0; o2 >>= 1) {
        pl += __shfl_xor(pl, o2);
        pr += __shfl_xor(pr, o2);
      }
      int row = row0 + r;
      if (l16 == 0 && row < M) {
        el[row * 4 + hb] = pl;
        er[row * 4 + hb] = pr;
      }
    }
  }

#pragma unroll
  for (int nt = 0; nt < 4; ++nt) {
    int col = bn + nt * 16 + l16;
#pragma unroll
    for (int r = 0; r < 4; ++r) {
      int row = row0 + r;
      if (row < M) {
        float v = acc[nt][r];
        if (col < 256)
          ft[(size_t)row * 256 + col] = (__bf16)v;
        else
          base[(size_t)row * 256 + (col - 256)] = (__bf16)(v + bias[col - 256]);
      }
    }
  }
}

// ---------------------------------------------------------------- edge scores
// writes scores in CSR slot order (pos[e]) so agg staging is coalesced
__global__ __launch_bounds__(256) void edge_kernel(const float* __restrict__ ef,
                                                   const int* __restrict__ src,
                                                   const int* __restrict__ dst,
                                                   const int* __restrict__ pos,
                                                   const float* __restrict__ Ve,
                                                   const float* __restrict__ el,
                                                   const float* __restrict__ er,
                                                   float* __restrict__ esc) {
  __shared__ float Vs[256];
  Vs[threadIdx.x] = Ve[threadIdx.x];
  __syncthreads();
  int e = blockIdx.x * 256 + threadIdx.x;
  if (e >= EE) return;
  float eh0 = 0, eh1 = 0, eh2 = 0, eh3 = 0;
  const float* row = ef + (size_t)e * 64;
#pragma unroll
  for (int i0 = 0; i0 < 64; i0 += 4) {
    float4 v = *(const float4*)(row + i0);
    float xs[4] = {v.x, v.y, v.z, v.w};
#pragma unroll
    for (int j = 0; j < 4; ++j) {
      float x = xs[j];
      const float* vp = &Vs[(i0 + j) * 4];
      eh0 += x * vp[0];
      eh1 += x * vp[1];
      eh2 += x * vp[2];
      eh3 += x * vp[3];
    }
  }
  int s = src[e], d = dst[e];
  float4 l = *(const float4*)(el + (size_t)s * 4);
  float4 r = *(const float4*)(er + (size_t)d * 4);
  float4 o;
  o.x = l.x + r.x + eh0;
  o.y = l.y + r.y + eh1;
  o.z = l.z + r.z + eh2;
  o.w = l.w + r.w + eh3;
  o.x = o.x > 0.f ? o.x : 0.2f * o.x;
  o.y = o.y > 0.f ? o.y : 0.2f * o.y;
  o.z = o.z > 0.f ? o.z : 0.2f * o.z;
  o.w = o.w > 0.f ? o.w : 0.2f * o.w;
  int p = pos[e];
  *(float4*)(esc + (size_t)p * 4) = o;
}

// ---------------------------------------------------------------- softmax-agg
// One block per dst node; wave = head. LDS-staged edges (coalesced CSR reads),
// online softmax across chunks, 4-way MLP ft gather.
// LAYER 0: +prev(base), ELU -> outb bf16 (may alias prev; same-slot RMW only).
// LAYER 1: +prev(h1)+bias, mean heads -> outf fp32.
template <int LAYER>
__global__ __launch_bounds__(256) void agg_kernel(const int* __restrict__ off,
                                                  const int* __restrict__ srcc,
                                                  const float* __restrict__ esc,
                                                  const __bf16* __restrict__ ft,
                                                  const __bf16* prev,
                                                  const float* __restrict__ bias,
                                                  __bf16* outb,
                                                  float* __restrict__ outf) {
  __shared__ int s_src[CHUNK];
  __shared__ float s_e[CHUNK * 4];
  __shared__ float red[256];
  int n = blockIdx.x;
  int t = threadIdx.x, h = t >> 6, lane = t & 63;
  int beg = off[n], end = off[n + 1];
  int deg = end - beg;
  float pv = (float)prev[(size_t)n * 256 + t];        // prefetched early
  float bv = (LAYER == 1) ? bias[t] : 0.f;
  int offd = h * 64 + lane;

  float m = -1e30f, den = 0.f, acc = 0.f;
  for (int c0 = 0; c0 < deg; c0 += CHUNK) {
    int c = min(CHUNK, deg - c0);
    for (int j = t; j < c; j += 256) {
      s_src[j] = srcc[beg + c0 + j];
      *(float4*)&s_e[j * 4] = *(const float4*)&esc[(size_t)(beg + c0 + j) * 4];
    }
    __syncthreads();
    float mc = -1e30f;
    for (int j = lane; j < c; j += 64) mc = fmaxf(mc, s_e[j * 4 + h]);
#pragma unroll
    for (int o2 = 32; o2 > 0; o2 >>= 1) mc = fmaxf(mc, __shfl_xor(mc, o2));
    float mn = fmaxf(m, mc);
    float rs = __expf(m - mn);   // 0 on first chunk (m=-1e30), 1 if max unchanged
    den *= rs;
    acc *= rs;
    m = mn;
    float dc = 0.f;
    for (int j = lane; j < c; j += 64) dc += __expf(s_e[j * 4 + h] - m);
#pragma unroll
    for (int o2 = 32; o2 > 0; o2 >>= 1) dc += __shfl_xor(dc, o2);
    den += dc;
    int j = 0;
    for (; j + 4 <= c; j += 4) {
      int s0 = s_src[j], s1 = s_src[j + 1], s2 = s_src[j + 2], s3 = s_src[j + 3];
      float w0 = __expf(s_e[(j + 0) * 4 + h] - m);
      float w1 = __expf(s_e[(j + 1) * 4 + h] - m);
      float w2 = __expf(s_e[(j + 2) * 4 + h] - m);
      float w3 = __expf(s_e[(j + 3) * 4 + h] - m);
      float v0 = (float)ft[(size_t)s0 * 256 + offd];
      float v1 = (float)ft[(size_t)s1 * 256 + offd];
      float v2 = (float)ft[(size_t)s2 * 256 + offd];
      float v3 = (float)ft[(size_t)s3 * 256 + offd];
      acc += w0 * v0;
      acc += w1 * v1;
      acc += w2 * v2;
      acc += w3 * v3;
    }
    for (; j < c; ++j)
      acc += __expf(s_e[j * 4 + h] - m) * (float)ft[(size_t)s_src[j] * 256 + offd];
    __syncthreads();
  }
  float res = (deg > 0) ? acc / den : 0.f;

  if (LAYER == 0) {
    float v = res + pv;
    v = v > 0.f ? v : (__expf(v) - 1.0f);  // ELU
    outb[(size_t)n * 256 + t] = (__bf16)v;
  } else {
    red[t] = res + pv + bv;
    __syncthreads();
    if (t < 64)
      outf[(size_t)n * 64 + t] =
          0.25f * (red[t] + red[t + 64] + red[t + 128] + red[t + 192]);
  }
}

// ---------------------------------------------------------------- launch
extern "C" void kernel_launch(void* const* d_in, const int* in_sizes, int n_in,
                              void* d_out, int out_size, void* d_ws, size_t ws_size,
                              hipStream_t stream) {
  const float* features  = (const float*)d_in[0];
  const float* edge_feat = (const float*)d_in[1];
  const int*   src       = (const int*)d_in[2];
  const int*   dst       = (const int*)d_in[3];
  const float* W0    = (const float*)d_in[4];
  const float* We0   = (const float*)d_in[5];
  const float* al0   = (const float*)d_in[6];
  const float* ar0   = (const float*)d_in[7];
  const float* ae0   = (const float*)d_in[8];
  const float* b0    = (const float*)d_in[9];
  const float* Wres0 = (const float*)d_in[10];
  const float* W1    = (const float*)d_in[11];
  const float* We1   = (const float*)d_in[12];
  const float* al1   = (const float*)d_in[13];
  const float* ar1   = (const float*)d_in[14];
  const float* ae1   = (const float*)d_in[15];
  const float* b1    = (const float*)d_in[16];
  float* out = (float*)d_out;

  char* ws = (char*)d_ws;
  size_t o = 0;
  auto alloc = [&](size_t bytes) {
    void* p = ws + o;
    o = (o + bytes + 255) & ~(size_t)255;
    return p;
  };
  int*    cnt      = (int*)alloc((size_t)NN * 4);
  int*    scanbuf  = (int*)alloc((size_t)NN * 4);
  int*    blocksum = (int*)alloc(256 * 4);
  int*    blockoff = (int*)alloc(256 * 4);
  int*    off      = (int*)alloc((size_t)(NN + 1) * 4);
  int*    cur      = (int*)alloc((size_t)NN * 4);
  int*    pos      = (int*)alloc((size_t)EE * 4);
  int*    srcc     = (int*)alloc((size_t)EE * 4);
  float*  esc      = (float*)alloc((size_t)EE * 4 * 4);
  float*  el       = (float*)alloc((size_t)NN * 4 * 4);
  float*  er       = (float*)alloc((size_t)NN * 4 * 4);
  float*  Ve0      = (float*)alloc(256 * 4);
  float*  Ve1      = (float*)alloc(256 * 4);
  __bf16* Bt0      = (__bf16*)alloc((size_t)512 * 64 * 2);
  __bf16* Bt1      = (__bf16*)alloc((size_t)256 * 256 * 2);
  __bf16* fbf      = (__bf16*)alloc((size_t)NN * 64 * 2);
  __bf16* ft       = (__bf16*)alloc((size_t)NN * 256 * 2);
  __bf16* base     = (__bf16*)alloc((size_t)NN * 256 * 2);  // h1 aliases base
  __bf16* h1       = base;

  const int EB = (EE + 255) / 256;   // 1563
  const int NB = (NN + 255) / 256;   // 196
  const int MG = (NN + 63) / 64;     // 782

  // prep (independent of everything)
  prep_kernel<<<1563 + 128 + 256 + 2, 256, 0, stream>>>(
      features, fbf, W0, Wres0, Bt0, W1, Bt1, We0, ae0, Ve0, We1, ae1, Ve1);

  // CSR by dst (shared by both layers)
  hipMemsetAsync(cnt, 0, (size_t)NN * 4, stream);
  count_kernel<<<EB, 256, 0, stream>>>(dst, cnt);
  scan1_kernel<<<NB, 256, 0, stream>>>(cnt, scanbuf, blocksum);
  scan2_kernel<<<1, 256, 0, stream>>>(blocksum, blockoff, NB);
  scan3_kernel<<<NB, 256, 0, stream>>>(scanbuf, cnt, blockoff, off, cur);
  fill_kernel<<<EB, 256, 0, stream>>>(src, dst, cur, pos, srcc);

  // ---- layer 0
  gemm_kernel<<<dim3(MG, 8), 256, 0, stream>>>(fbf, Bt0, ft, base, b0, al0, ar0, el, er, NN, 64);
  edge_kernel<<<EB, 256, 0, stream>>>(edge_feat, src, dst, pos, Ve0, el, er, esc);
  agg_kernel<0><<<NN, 256, 0, stream>>>(off, srcc, esc, ft, base, nullptr, h1, nullptr);

  // ---- layer 1
  gemm_kernel<<<dim3(MG, 4), 256, 0, stream>>>(h1, Bt1, ft, nullptr, nullptr, al1, ar1, el, er, NN, 256);
  edge_kernel<<<EB, 256, 0, stream>>>(edge_feat, src, dst, pos, Ve1, el, er, esc);
  agg_kernel<1><<<NN, 256, 0, stream>>>(off, srcc, esc, ft, h1, b1, nullptr, out);
}

// Round 4
// 458.265 us; speedup vs baseline: 1.6074x; 1.0959x over previous
//
#include <hip/hip_runtime.h>
#include <hip/hip_bf16.h>

#define NN 50000
#define EE 400000

typedef __bf16 bf16_8 __attribute__((ext_vector_type(8)));
typedef float f32x4 __attribute__((ext_vector_type(4)));

// ---------------------------------------------------------------- CSR scan
__global__ __launch_bounds__(256) void scan1_kernel(const int* __restrict__ cnt,
                                                    int* __restrict__ scanbuf,
                                                    int* __restrict__ blocksum) {
  __shared__ int s[256];
  int t = threadIdx.x;
  int idx = blockIdx.x * 256 + t;
  int c = (idx < NN) ? cnt[idx] : 0;
  s[t] = c;
  __syncthreads();
  for (int d = 1; d < 256; d <<= 1) {
    int v = (t >= d) ? s[t - d] : 0;
    __syncthreads();
    s[t] += v;
    __syncthreads();
  }
  if (idx < NN) scanbuf[idx] = s[t];
  if (t == 255) blocksum[blockIdx.x] = s[255];
}

__global__ __launch_bounds__(256) void scan2_kernel(const int* __restrict__ blocksum,
                                                    int* __restrict__ blockoff, int nb) {
  __shared__ int s[256];
  int t = threadIdx.x;
  int c = (t < nb) ? blocksum[t] : 0;
  s[t] = c;
  __syncthreads();
  for (int d = 1; d < 256; d <<= 1) {
    int v = (t >= d) ? s[t - d] : 0;
    __syncthreads();
    s[t] += v;
    __syncthreads();
  }
  if (t < nb) blockoff[t] = s[t] - c;  // exclusive
}

__global__ __launch_bounds__(256) void scan3_kernel(const int* __restrict__ scanbuf,
                                                    const int* __restrict__ cnt,
                                                    const int* __restrict__ blockoff,
                                                    int* __restrict__ off,
                                                    int* __restrict__ cur) {
  int idx = blockIdx.x * 256 + threadIdx.x;
  if (idx < NN) {
    int o = blockoff[blockIdx.x] + scanbuf[idx] - cnt[idx];
    off[idx] = o;
    cur[idx] = o;
  }
  if (idx == 0) off[NN] = EE;
}

// records pos[e], src_csr[p], dst_csr[p]
__global__ __launch_bounds__(256) void fill_kernel(const int* __restrict__ src,
                                                   const int* __restrict__ dst,
                                                   int* __restrict__ cur,
                                                   int* __restrict__ pos,
                                                   int* __restrict__ srcc,
                                                   int* __restrict__ dstc) {
  int e = blockIdx.x * 256 + threadIdx.x;
  if (e < EE) {
    int d = dst[e];
    int p = atomicAdd(&cur[d], 1);
    pos[e] = p;
    srcc[p] = src[e];
    dstc[p] = d;
  }
}

// ---------------------------------------------------------------- prep (fused)
// [0,1563): f2b; [1563,1691): tr0; [1691,1947): tr1; 1947: ve0; 1948: ve1;
// [1949, 1949+1563): degree count (cnt zeroed by memset before launch)
__global__ __launch_bounds__(256) void prep_kernel(
    const float* __restrict__ features, __bf16* __restrict__ fbf,
    const float* __restrict__ W0, const float* __restrict__ Wres0, __bf16* __restrict__ Bt0,
    const float* __restrict__ W1, __bf16* __restrict__ Bt1,
    const float* __restrict__ We0, const float* __restrict__ ae0, float* __restrict__ Ve0,
    const float* __restrict__ We1, const float* __restrict__ ae1, float* __restrict__ Ve1,
    const int* __restrict__ dst, int* __restrict__ cnt) {
  int b = blockIdx.x;
  int t = threadIdx.x;
  if (b < 1563) {                       // fp32 -> bf16, 8 elems/thread
    int i = b * 256 + t;
    if (i < NN * 64 / 8) {
      const float4* p = (const float4*)features + (size_t)i * 2;
      float4 a = p[0], c = p[1];
      bf16_8 v = {(__bf16)a.x, (__bf16)a.y, (__bf16)a.z, (__bf16)a.w,
                  (__bf16)c.x, (__bf16)c.y, (__bf16)c.z, (__bf16)c.w};
      *(bf16_8*)(fbf + (size_t)i * 8) = v;
    }
  } else if (b < 1563 + 128) {          // Bt0 (512x64): W0^T | Wres0^T
    int idx = (b - 1563) * 256 + t;
    int j = idx >> 6, k = idx & 63;
    float v = (j < 256) ? W0[k * 256 + j] : Wres0[k * 256 + (j - 256)];
    Bt0[idx] = (__bf16)v;
  } else if (b < 1563 + 128 + 256) {    // Bt1 (256x256) = W1^T
    int idx = (b - 1563 - 128) * 256 + t;
    int j = idx >> 8, k = idx & 255;
    Bt1[idx] = (__bf16)W1[k * 256 + j];
  } else if (b == 1947) {               // Ve0
    int f = t >> 2, h = t & 3;
    float s = 0.f;
    for (int d = 0; d < 64; ++d) s += We0[f * 256 + h * 64 + d] * ae0[h * 64 + d];
    Ve0[f * 4 + h] = s;
  } else if (b == 1948) {               // Ve1
    int f = t >> 2, h = t & 3;
    float s = 0.f;
    for (int d = 0; d < 64; ++d) s += We1[f * 256 + h * 64 + d] * ae1[h * 64 + d];
    Ve1[f * 4 + h] = s;
  } else {                              // degree count
    int e = (b - 1949) * 256 + t;
    if (e < EE) atomicAdd(&cnt[dst[e]], 1);
  }
}

// ---------------------------------------------------------------- MFMA GEMM
// C[M x NC] = A @ B, Bt: NC x K row-major. cols<256 -> ft (bf16) + fused el/er;
// cols>=256 -> base = val + bias[col-256] (layer 0 residual).
#define LDK 40
__global__ __launch_bounds__(256) void gemm_kernel(const __bf16* __restrict__ A,
                                                   const __bf16* __restrict__ Bt,
                                                   __bf16* __restrict__ ft,
                                                   __bf16* __restrict__ base,
                                                   const float* __restrict__ bias,
                                                   const float* __restrict__ al,
                                                   const float* __restrict__ ar,
                                                   float* __restrict__ el,
                                                   float* __restrict__ er,
                                                   int M, int K) {
  __shared__ __align__(16) __bf16 Al[64 * LDK];
  __shared__ __align__(16) __bf16 Bl[64 * LDK];
  int tid = threadIdx.x;
  int wav = tid >> 6, lane = tid & 63;
  int quad = lane >> 4, l16 = lane & 15;
  int bm = blockIdx.x * 64;
  int bn = blockIdx.y * 64;
  int sr = tid >> 2;
  int sk = (tid & 3) << 3;

  f32x4 acc[4] = {{0, 0, 0, 0}, {0, 0, 0, 0}, {0, 0, 0, 0}, {0, 0, 0, 0}};

  for (int k0 = 0; k0 < K; k0 += 32) {
    uint4 av = {0, 0, 0, 0};
    int arow = bm + sr;
    if (arow < M) av = *(const uint4*)(A + (size_t)arow * K + k0 + sk);
    uint4 bv = *(const uint4*)(Bt + (size_t)(bn + sr) * K + k0 + sk);
    __syncthreads();
    *(uint4*)&Al[sr * LDK + sk] = av;
    *(uint4*)&Bl[sr * LDK + sk] = bv;
    __syncthreads();
    bf16_8 af = *(const bf16_8*)&Al[(wav * 16 + l16) * LDK + quad * 8];
#pragma unroll
    for (int nt = 0; nt < 4; ++nt) {
      bf16_8 bf = *(const bf16_8*)&Bl[(nt * 16 + l16) * LDK + quad * 8];
      acc[nt] = __builtin_amdgcn_mfma_f32_16x16x32_bf16(af, bf, acc[nt], 0, 0, 0);
    }
  }

  int row0 = bm + wav * 16 + quad * 4;

  // fused el/er for head hb = bn/64 (cols < 256 only)
  if (bn < 256) {
    int hb = bn >> 6;
#pragma unroll
    for (int r = 0; r < 4; ++r) {
      float pl = 0.f, pr = 0.f;
#pragma unroll
      for (int nt = 0; nt < 4; ++nt) {
        float v = acc[nt][r];
        int d = nt * 16 + l16;
        pl += v * al[hb * 64 + d];
        pr += v * ar[hb * 64 + d];
      }
#pragma unroll
      for (int o2 = 8; o2 > 0; o2 >>= 1) {
        pl += __shfl_xor(pl, o2);
        pr += __shfl_xor(pr, o2);
      }
      int row = row0 + r;
      if (l16 == 0 && row < M) {
        el[row * 4 + hb] = pl;
        er[row * 4 + hb] = pr;
      }
    }
  }

#pragma unroll
  for (int nt = 0; nt < 4; ++nt) {
    int col = bn + nt * 16 + l16;
#pragma unroll
    for (int r = 0; r < 4; ++r) {
      int row = row0 + r;
      if (row < M) {
        float v = acc[nt][r];
        if (col < 256)
          ft[(size_t)row * 256 + col] = (__bf16)v;
        else
          base[(size_t)row * 256 + (col - 256)] = (__bf16)(v + bias[col - 256]);
      }
    }
  }
}

// ---------------------------------------------------------------- edge pass, layer 0
// Single read of edge_feat: w0 = exp(leaky(el0+er0+ef.Ve0)) -> esc[pos] (CSR order);
// also ee1 = ef.Ve1 -> ee1c[pos] for layer 1.
__global__ __launch_bounds__(256) void edge0_kernel(const float* __restrict__ ef,
                                                    const int* __restrict__ src,
                                                    const int* __restrict__ dst,
                                                    const int* __restrict__ pos,
                                                    const float* __restrict__ Ve0,
                                                    const float* __restrict__ Ve1,
                                                    const float* __restrict__ el,
                                                    const float* __restrict__ er,
                                                    float* __restrict__ esc,
                                                    float* __restrict__ ee1c) {
  __shared__ float V0[256], V1[256];
  V0[threadIdx.x] = Ve0[threadIdx.x];
  V1[threadIdx.x] = Ve1[threadIdx.x];
  __syncthreads();
  int e = blockIdx.x * 256 + threadIdx.x;
  if (e >= EE) return;
  float a0 = 0, a1 = 0, a2 = 0, a3 = 0;  // layer-0 ee
  float c0 = 0, c1 = 0, c2 = 0, c3 = 0;  // layer-1 ee
  const float* row = ef + (size_t)e * 64;
#pragma unroll
  for (int i0 = 0; i0 < 64; i0 += 4) {
    float4 v = *(const float4*)(row + i0);
    float xs[4] = {v.x, v.y, v.z, v.w};
#pragma unroll
    for (int j = 0; j < 4; ++j) {
      float x = xs[j];
      const float* p0 = &V0[(i0 + j) * 4];
      const float* p1 = &V1[(i0 + j) * 4];
      a0 += x * p0[0]; a1 += x * p0[1]; a2 += x * p0[2]; a3 += x * p0[3];
      c0 += x * p1[0]; c1 += x * p1[1]; c2 += x * p1[2]; c3 += x * p1[3];
    }
  }
  int s = src[e], d = dst[e];
  float4 l = *(const float4*)(el + (size_t)s * 4);
  float4 r = *(const float4*)(er + (size_t)d * 4);
  float4 o;
  o.x = l.x + r.x + a0;
  o.y = l.y + r.y + a1;
  o.z = l.z + r.z + a2;
  o.w = l.w + r.w + a3;
  o.x = __expf(o.x > 0.f ? o.x : 0.2f * o.x);
  o.y = __expf(o.y > 0.f ? o.y : 0.2f * o.y);
  o.z = __expf(o.z > 0.f ? o.z : 0.2f * o.z);
  o.w = __expf(o.w > 0.f ? o.w : 0.2f * o.w);
  int p = pos[e];
  *(float4*)(esc + (size_t)p * 4) = o;
  float4 c;
  c.x = c0; c.y = c1; c.z = c2; c.w = c3;
  *(float4*)(ee1c + (size_t)p * 4) = c;
}

// ---------------------------------------------------------------- edge pass, layer 1
// slot-parallel (already CSR order): w1 = exp(leaky(el1[srcc]+er1[dstc]+ee1c))
__global__ __launch_bounds__(256) void edge1_kernel(const int* __restrict__ srcc,
                                                    const int* __restrict__ dstc,
                                                    const float* __restrict__ ee1c,
                                                    const float* __restrict__ el,
                                                    const float* __restrict__ er,
                                                    float* __restrict__ esc) {
  int p = blockIdx.x * 256 + threadIdx.x;
  if (p >= EE) return;
  int s = srcc[p], d = dstc[p];
  float4 c = *(const float4*)(ee1c + (size_t)p * 4);
  float4 l = *(const float4*)(el + (size_t)s * 4);
  float4 r = *(const float4*)(er + (size_t)d * 4);
  float4 o;
  o.x = l.x + r.x + c.x;
  o.y = l.y + r.y + c.y;
  o.z = l.z + r.z + c.z;
  o.w = l.w + r.w + c.w;
  o.x = __expf(o.x > 0.f ? o.x : 0.2f * o.x);
  o.y = __expf(o.y > 0.f ? o.y : 0.2f * o.y);
  o.z = __expf(o.z > 0.f ? o.z : 0.2f * o.z);
  o.w = __expf(o.w > 0.f ? o.w : 0.2f * o.w);
  *(float4*)(esc + (size_t)p * 4) = o;
}

// ---------------------------------------------------------------- agg
// One block per dst node; wave = head. esc holds exp'd weights in CSR order.
// Single pass: acc += w*v (gather), den += w (wave-uniform). No barriers/LDS
// in the loop. LAYER 0: +prev, ELU -> outb bf16 (aliases prev; same-slot RMW).
// LAYER 1: +prev+bias, mean heads -> outf fp32.
template <int LAYER>
__global__ __launch_bounds__(256) void agg_kernel(const int* __restrict__ off,
                                                  const int* __restrict__ srcc,
                                                  const float* __restrict__ esc,
                                                  const __bf16* __restrict__ ft,
                                                  const __bf16* prev,
                                                  const float* __restrict__ bias,
                                                  __bf16* outb,
                                                  float* __restrict__ outf) {
  __shared__ float red[256];
  int n = blockIdx.x;
  int t = threadIdx.x, h = t >> 6, lane = t & 63;
  int beg = off[n], end = off[n + 1];
  float pv = (float)prev[(size_t)n * 256 + t];
  float bv = (LAYER == 1) ? bias[t] : 0.f;
  int offd = h * 64 + lane;

  float acc = 0.f, den = 0.f;
  int j = beg;
  for (; j + 4 <= end; j += 4) {
    int s0 = srcc[j], s1 = srcc[j + 1], s2 = srcc[j + 2], s3 = srcc[j + 3];
    float w0 = esc[(size_t)(j + 0) * 4 + h];
    float w1 = esc[(size_t)(j + 1) * 4 + h];
    float w2 = esc[(size_t)(j + 2) * 4 + h];
    float w3 = esc[(size_t)(j + 3) * 4 + h];
    float v0 = (float)ft[(size_t)s0 * 256 + offd];
    float v1 = (float)ft[(size_t)s1 * 256 + offd];
    float v2 = (float)ft[(size_t)s2 * 256 + offd];
    float v3 = (float)ft[(size_t)s3 * 256 + offd];
    acc += w0 * v0; acc += w1 * v1; acc += w2 * v2; acc += w3 * v3;
    den += w0 + w1 + w2 + w3;
  }
  for (; j < end; ++j) {
    float w = esc[(size_t)j * 4 + h];
    acc += w * (float)ft[(size_t)srcc[j] * 256 + offd];
    den += w;
  }
  float res = (end > beg) ? acc / den : 0.f;

  if (LAYER == 0) {
    float v = res + pv;
    v = v > 0.f ? v : (__expf(v) - 1.0f);  // ELU
    outb[(size_t)n * 256 + t] = (__bf16)v;
  } else {
    red[t] = res + pv + bv;
    __syncthreads();
    if (t < 64)
      outf[(size_t)n * 64 + t] =
          0.25f * (red[t] + red[t + 64] + red[t + 128] + red[t + 192]);
  }
}

// ---------------------------------------------------------------- launch
extern "C" void kernel_launch(void* const* d_in, const int* in_sizes, int n_in,
                              void* d_out, int out_size, void* d_ws, size_t ws_size,
                              hipStream_t stream) {
  const float* features  = (const float*)d_in[0];
  const float* edge_feat = (const float*)d_in[1];
  const int*   src       = (const int*)d_in[2];
  const int*   dst       = (const int*)d_in[3];
  const float* W0    = (const float*)d_in[4];
  const float* We0   = (const float*)d_in[5];
  const float* al0   = (const float*)d_in[6];
  const float* ar0   = (const float*)d_in[7];
  const float* ae0   = (const float*)d_in[8];
  const float* b0    = (const float*)d_in[9];
  const float* Wres0 = (const float*)d_in[10];
  const float* W1    = (const float*)d_in[11];
  const float* We1   = (const float*)d_in[12];
  const float* al1   = (const float*)d_in[13];
  const float* ar1   = (const float*)d_in[14];
  const float* ae1   = (const float*)d_in[15];
  const float* b1    = (const float*)d_in[16];
  float* out = (float*)d_out;

  char* ws = (char*)d_ws;
  size_t o = 0;
  auto alloc = [&](size_t bytes) {
    void* p = ws + o;
    o = (o + bytes + 255) & ~(size_t)255;
    return p;
  };
  int*    cnt      = (int*)alloc((size_t)NN * 4);
  int*    scanbuf  = (int*)alloc((size_t)NN * 4);
  int*    blocksum = (int*)alloc(256 * 4);
  int*    blockoff = (int*)alloc(256 * 4);
  int*    off      = (int*)alloc((size_t)(NN + 1) * 4);
  int*    cur      = (int*)alloc((size_t)NN * 4);
  int*    pos      = (int*)alloc((size_t)EE * 4);
  int*    srcc     = (int*)alloc((size_t)EE * 4);
  int*    dstc     = (int*)alloc((size_t)EE * 4);
  float*  esc      = (float*)alloc((size_t)EE * 4 * 4);
  float*  ee1c     = (float*)alloc((size_t)EE * 4 * 4);
  float*  el       = (float*)alloc((size_t)NN * 4 * 4);
  float*  er       = (float*)alloc((size_t)NN * 4 * 4);
  float*  Ve0      = (float*)alloc(256 * 4);
  float*  Ve1      = (float*)alloc(256 * 4);
  __bf16* Bt0      = (__bf16*)alloc((size_t)512 * 64 * 2);
  __bf16* Bt1      = (__bf16*)alloc((size_t)256 * 256 * 2);
  __bf16* fbf      = (__bf16*)alloc((size_t)NN * 64 * 2);
  __bf16* ft       = (__bf16*)alloc((size_t)NN * 256 * 2);
  __bf16* base     = (__bf16*)alloc((size_t)NN * 256 * 2);  // h1 aliases base
  __bf16* h1       = base;

  const int EB = (EE + 255) / 256;   // 1563
  const int NB = (NN + 255) / 256;   // 196
  const int MG = (NN + 63) / 64;     // 782

  // prep (f2b, weight transposes, Ve0/Ve1, degree count)
  hipMemsetAsync(cnt, 0, (size_t)NN * 4, stream);
  prep_kernel<<<1949 + EB, 256, 0, stream>>>(features, fbf, W0, Wres0, Bt0, W1, Bt1,
                                             We0, ae0, Ve0, We1, ae1, Ve1, dst, cnt);
  scan1_kernel<<<NB, 256, 0, stream>>>(cnt, scanbuf, blocksum);
  scan2_kernel<<<1, 256, 0, stream>>>(blocksum, blockoff, NB);
  scan3_kernel<<<NB, 256, 0, stream>>>(scanbuf, cnt, blockoff, off, cur);
  fill_kernel<<<EB, 256, 0, stream>>>(src, dst, cur, pos, srcc, dstc);

  // ---- layer 0
  gemm_kernel<<<dim3(MG, 8), 256, 0, stream>>>(fbf, Bt0, ft, base, b0, al0, ar0, el, er, NN, 64);
  edge0_kernel<<<EB, 256, 0, stream>>>(edge_feat, src, dst, pos, Ve0, Ve1, el, er, esc, ee1c);
  agg_kernel<0><<<NN, 256, 0, stream>>>(off, srcc, esc, ft, base, nullptr, h1, nullptr);

  // ---- layer 1
  gemm_kernel<<<dim3(MG, 4), 256, 0, stream>>>(h1, Bt1, ft, nullptr, nullptr, al1, ar1, el, er, NN, 256);
  edge1_kernel<<<EB, 256, 0, stream>>>(srcc, dstc, ee1c, el, er, esc);
  agg_kernel<1><<<NN, 256, 0, stream>>>(off, srcc, esc, ft, h1, b1, nullptr, out);
}